// Round 3
// baseline (307.509 us; speedup 1.0000x reference)
//
#include <hip/hip_runtime.h>

typedef __bf16 bf16_t;
typedef __bf16 bf16x8 __attribute__((ext_vector_type(8)));
typedef float f32x4 __attribute__((ext_vector_type(4)));
typedef unsigned int u32x4 __attribute__((ext_vector_type(4)));

#define KDIM 512
#define NDIM 512
#define BM 128
#define BN 128
#define BK 32

// async 16B global->LDS. LDS dest must be wave-uniform base; HW scatters lane*16.
__device__ __forceinline__ void gld_lds16(const float* g, float* lds_uniform) {
  __builtin_amdgcn_global_load_lds(
      (const __attribute__((address_space(1))) void*)g,
      (__attribute__((address_space(3))) void*)lds_uniform, 16, 0, 0);
}

__device__ __forceinline__ bf16x8 neg8(bf16x8 v) {
  union { bf16x8 b; u32x4 u; } x;
  x.b = v;
  x.u = x.u ^ 0x80008000u;  // flip bf16 sign bits (packed)
  return x.b;
}

// Read one A fragment (8 fp32 along k) from the granule-swizzled fp32 LDS tile
// and convert to bf16x8. slot(row, g') holds global granule g = g'^(row&7);
// granule = 16 B. Bank = f(slot) only -> 2-way alias max (free per m136).
__device__ __forceinline__ bf16x8 afrag(const float* ldsx, int r, int h4) {
  const int base = r * 8;
  const int sw = r & 7;
  const float4 a = *(const float4*)(ldsx + 4 * (base + ((2 * h4) ^ sw)));
  const float4 b = *(const float4*)(ldsx + 4 * (base + ((2 * h4 + 1) ^ sw)));
  bf16x8 f;
  f[0] = (__bf16)a.x; f[1] = (__bf16)a.y; f[2] = (__bf16)a.z; f[3] = (__bf16)a.w;
  f[4] = (__bf16)b.x; f[5] = (__bf16)b.y; f[6] = (__bf16)b.z; f[7] = (__bf16)b.w;
  return f;
}

__device__ __forceinline__ bf16x8 pack8(float4 a, float4 b) {
  bf16x8 f;
  f[0] = (__bf16)a.x; f[1] = (__bf16)a.y; f[2] = (__bf16)a.z; f[3] = (__bf16)a.w;
  f[4] = (__bf16)b.x; f[5] = (__bf16)b.y; f[6] = (__bf16)b.z; f[7] = (__bf16)b.w;
  return f;
}

__global__ __launch_bounds__(256, 2) void dft_cgemm_kernel(
    const float* __restrict__ xr, const float* __restrict__ xi,
    const float* __restrict__ wre, const float* __restrict__ wim,
    float* __restrict__ out) {
  // x: fp32, DOUBLE-buffered (DMA target), granule-swizzled. 2*2*16KB = 64 KB.
  __shared__ __align__(16) float lds_x[2][2][BM * BK];
  // weights: bf16, fragment-ordered: slot(row,g) = (row>>4)*64 + g*16 + (row&15)
  __shared__ __align__(16) bf16_t lds_wr[BN * BK];  // 8 KB
  __shared__ __align__(16) bf16_t lds_wi[BN * BK];  // 8 KB
  // total 80 KB -> 2 blocks/CU (registers cap us at 2 anyway)

  const int t = threadIdx.x;
  const int lane = t & 63;
  const int wv = t >> 6;

  // XCD-aware swizzle: xcd owns 32 m-tiles x all 4 n-tiles -> x fetched once/XCD
  const int b = blockIdx.x;                 // 0..1023
  const int xcd = b & 7;
  const int sidx = b >> 3;
  const int m0 = (xcd * 32 + (sidx >> 2)) * BM;
  const int n0 = (sidx & 3) * BN;

  const int wm = (wv >> 1) * 64;
  const int wn = (wv & 1) * 64;
  const int l16 = lane & 15;
  const int h4 = lane >> 4;

  // ---- k0-invariant DMA source offsets + LDS dest offsets for x ----
  size_t goffx[4];
  int dofx[4];
#pragma unroll
  for (int it = 0; it < 4; ++it) {
    const int S = it * 256 + t;        // granule slot 0..1023
    const int row = S >> 3;
    const int g = (S & 7) ^ (row & 7); // swizzled global granule
    goffx[it] = (size_t)(m0 + row) * KDIM + g * 4;
    dofx[it] = 4 * (it * 256 + wv * 64);  // wave-uniform LDS base (floats)
  }

  // ---- weight staging coords (fragment-ordered): slot = c*256 + t ----
  const int wt15 = t & 15;
  const int wg = (t >> 4) & 3;
  const float* gwr[2];
  const float* gwi[2];
#pragma unroll
  for (int c = 0; c < 2; ++c) {
    const int row = (c * 4 + wv) * 16 + wt15;
    gwr[c] = wre + (size_t)(n0 + row) * KDIM + wg * 8;
    gwi[c] = wim + (size_t)(n0 + row) * KDIM + wg * 8;
  }

  f32x4 acc_re[4][4], acc_im[4][4];
#pragma unroll
  for (int i = 0; i < 4; ++i)
#pragma unroll
    for (int j = 0; j < 4; ++j) {
      acc_re[i][j] = (f32x4){0.f, 0.f, 0.f, 0.f};
      acc_im[i][j] = (f32x4){0.f, 0.f, 0.f, 0.f};
    }

  // ---- prologue: w(0) -> regs, DMA x(0) -> buf 0 ----
  float4 wreg[8];
#pragma unroll
  for (int c = 0; c < 2; ++c) {
    wreg[c * 4 + 0] = ((const float4*)(gwr[c]))[0];
    wreg[c * 4 + 1] = ((const float4*)(gwr[c]))[1];
    wreg[c * 4 + 2] = ((const float4*)(gwi[c]))[0];
    wreg[c * 4 + 3] = ((const float4*)(gwi[c]))[1];
  }
#pragma unroll
  for (int it = 0; it < 4; ++it) {
    gld_lds16(xr + goffx[it], &lds_x[0][0][dofx[it]]);
    gld_lds16(xi + goffx[it], &lds_x[0][1][dofx[it]]);
  }

  int cur = 0;
  for (int k0 = 0; k0 < KDIM; k0 += BK, cur ^= 1) {
    // B1: drains x-DMA(k) + w-loads(k) — both issued a full MFMA-section ago
    __syncthreads();

    // ds_write w(k) from regs (fragment-ordered, wave-contiguous)
#pragma unroll
    for (int c = 0; c < 2; ++c) {
      const int slot = c * 256 + t;
      *(bf16x8*)(lds_wr + slot * 8) = pack8(wreg[c * 4 + 0], wreg[c * 4 + 1]);
      *(bf16x8*)(lds_wi + slot * 8) = pack8(wreg[c * 4 + 2], wreg[c * 4 + 3]);
    }
    // B2: lgkm-only (no vmem issued since B1) — cheap
    __syncthreads();

    // issue next tile's global ops NOW; they drain at next B1, a full
    // ds_read+MFMA section from here (async prefetch across the barrier)
    const int kn = k0 + BK;
    if (kn < KDIM) {
#pragma unroll
      for (int it = 0; it < 4; ++it) {
        gld_lds16(xr + goffx[it] + kn, &lds_x[cur ^ 1][0][dofx[it]]);
        gld_lds16(xi + goffx[it] + kn, &lds_x[cur ^ 1][1][dofx[it]]);
      }
#pragma unroll
      for (int c = 0; c < 2; ++c) {
        wreg[c * 4 + 0] = ((const float4*)(gwr[c] + kn))[0];
        wreg[c * 4 + 1] = ((const float4*)(gwr[c] + kn))[1];
        wreg[c * 4 + 2] = ((const float4*)(gwi[c] + kn))[0];
        wreg[c * 4 + 3] = ((const float4*)(gwi[c] + kn))[1];
      }
    }

    // ---- fragments for tile k ----
    const float* ldsxr = lds_x[cur][0];
    const float* ldsxi = lds_x[cur][1];
    bf16x8 ar[4], ai[4], br[4], bi[4];
#pragma unroll
    for (int mi = 0; mi < 4; ++mi) {
      const int r = wm + mi * 16 + l16;
      ar[mi] = afrag(ldsxr, r, h4);
      ai[mi] = afrag(ldsxi, r, h4);
    }
#pragma unroll
    for (int ni = 0; ni < 4; ++ni) {
      const int slot = ((wn >> 4) + ni) * 64 + h4 * 16 + l16;
      br[ni] = *(const bf16x8*)(lds_wr + slot * 8);
      bi[ni] = *(const bf16x8*)(lds_wi + slot * 8);
    }

    // re += xr*wr - xi*wi ; im += xr*wi + xi*wr   (nai short-lived: low VGPR)
#pragma unroll
    for (int mi = 0; mi < 4; ++mi) {
      const bf16x8 nai = neg8(ai[mi]);
#pragma unroll
      for (int ni = 0; ni < 4; ++ni) {
        acc_re[mi][ni] = __builtin_amdgcn_mfma_f32_16x16x32_bf16(ar[mi], br[ni], acc_re[mi][ni], 0, 0, 0);
        acc_im[mi][ni] = __builtin_amdgcn_mfma_f32_16x16x32_bf16(ar[mi], bi[ni], acc_im[mi][ni], 0, 0, 0);
        acc_re[mi][ni] = __builtin_amdgcn_mfma_f32_16x16x32_bf16(nai,    bi[ni], acc_re[mi][ni], 0, 0, 0);
        acc_im[mi][ni] = __builtin_amdgcn_mfma_f32_16x16x32_bf16(ai[mi], br[ni], acc_im[mi][ni], 0, 0, 0);
      }
    }
  }

  // ---- epilogue: interleaved (re, im) float2 stores, coalesced in h ----
#pragma unroll
  for (int mi = 0; mi < 4; ++mi) {
#pragma unroll
    for (int r = 0; r < 4; ++r) {
      const int m = m0 + wm + mi * 16 + h4 * 4 + r;  // C/D: row = (lane>>4)*4 + reg
#pragma unroll
      for (int ni = 0; ni < 4; ++ni) {
        const int h = n0 + wn + ni * 16 + l16;       // C/D: col = lane & 15
        float2 v;
        v.x = acc_re[mi][ni][r];
        v.y = acc_im[mi][ni][r];
        *(float2*)(out + ((size_t)m * NDIM + h) * 2) = v;
      }
    }
  }
}

extern "C" void kernel_launch(void* const* d_in, const int* in_sizes, int n_in,
                              void* d_out, int out_size, void* d_ws, size_t ws_size,
                              hipStream_t stream) {
  const float* xr  = (const float*)d_in[0];
  const float* xi  = (const float*)d_in[1];
  const float* wre = (const float*)d_in[2];
  const float* wim = (const float*)d_in[3];
  float* out = (float*)d_out;

  dim3 grid(1024);  // (m-tiles 256) x (n-tiles 4), XCD-swizzled inside kernel
  dim3 block(256);
  dft_cgemm_kernel<<<grid, block, 0, stream>>>(xr, xi, wre, wim, out);
}